// Round 3
// baseline (141.920 us; speedup 1.0000x reference)
//
#include <hip/hip_runtime.h>
#include <hip/hip_fp16.h>
#include <stdint.h>

// OrthogonalLinear: pyramid Givens circuit, n = m = 512, B = 256, T = 1021 layers.
// Layer t: gates (i,i+1), i = (t&1), (t&1)+2, ..., i <= min(t, 1020-t).
// theta idx: k = (t+i)/2 + 1, idx = k(k-1)/2 + (k-1-i).
//
// R13: windowed composition + MFMA apply.
//  - 511 layer-pairs (pair p = layers 2p, 2p+1; layer 1021 = identity).
//  - 9 windows: 8 x 57 pairs + 1 x 55 pairs (<=114 layers each).
//  - Light-cone: basis row d through <=114 layers has support within d +- 57,
//    so window matrix V_w is banded; a 128-wire aligned strip covers it.
//  - window_kernel: 16-lane groups evolve basis rows with the R12-proven
//    f16-gate pair machinery (row-DPP; out-of-strip values are exactly 0, so
//    row-edge zero fill == real circuit). Writes V_w transposed [col][row] f16.
//  - apply_kernel: out = x * V0 * ... * V8 as 9 banded GEMMs on matrix cores
//    (mfma 16x16x32 f16, f32 accum, state f32 in LDS ping-pong). Band +-57 < 64
//    => 64-col output tile needs k-tiles n-1..n+1 only (K<=192).

#define PAIRS   511
#define TOTALH2 (PAIRS * 512)       // gate half2 slots
#define NWIN    9
#define WPAIRS  57
#define VT_ELEMS (512 * 512)
#define VT_OFF_BYTES 1048576        // table = 511*128*16 = 1,046,528 B

typedef _Float16 half8_t __attribute__((ext_vector_type(8)));
typedef float f32x4_t __attribute__((ext_vector_type(4)));

// ---------------- kernel 1: f16 gate table (R12 layout, 511 uniform pairs) --
// uint4 idx = p*128 + h*64 + L; h=0: even-layer gates of wires 8L+{0,2,4,6};
// h=1: odd-layer gates 8L+{1,3,5}, .w = boundary gate (8L+7,8L+8) as (c-1,s).
// Dead slots identity. Pair 510 = (t=1020 real, t=1021 identity) via validity.
__global__ __launch_bounds__(256) void fused_kernel(
    const float* __restrict__ thetas, __half2* __restrict__ Wh) {
  int tid = blockIdx.x * 256 + threadIdx.x;   // grid exact: 511*512 threads
  int p = tid >> 9, r = tid & 511;
  int h = r >> 8, rr = r & 255, L = rr >> 2, j = rr & 3;
  int t = 2 * p + h;
  int i = 8 * L + 2 * j + h;
  float c = 1.0f, s = 0.0f;
  if (i <= min(t, 1020 - t)) {
    int k = ((t + i) >> 1) + 1;
    int idx = ((k * (k - 1)) >> 1) + (k - 1 - i);
    __sincosf(thetas[idx], &s, &c);
  }
  if (h == 1 && j == 3) c -= 1.0f;   // boundary gate stored as (c-1, s)
  Wh[tid] = __floats2half2_rn(c, s);
}

// ---------------- shared device helpers (R12-proven math) -------------------
template <int N>
__device__ __forceinline__ void wait_vm() {
  asm volatile("s_waitcnt vmcnt(%0)" ::"i"(N) : "memory");
}
template <int CTRL>
__device__ __forceinline__ float dpp_f(float v) {
  return __int_as_float(
      __builtin_amdgcn_mov_dpp(__float_as_int(v), CTRL, 0xF, 0xF, true));
}
template <int CTRL>
__device__ __forceinline__ uint32_t dpp_u(uint32_t v) {
  return (uint32_t)__builtin_amdgcn_mov_dpp((int)v, CTRL, 0xF, 0xF, true);
}
// d = f16hi(g) * b   (s*b)
__device__ __forceinline__ float mix_s(uint32_t g, float b) {
  float d;
  asm("v_fma_mix_f32 %0, %1, %2, 0 op_sel:[1,0,0] op_sel_hi:[1,0,0]"
      : "=v"(d) : "v"(g), "v"(b));
  return d;
}
// d = -f16hi(g) * b
__device__ __forceinline__ float mix_ns(uint32_t g, float b) {
  float d;
  asm("v_fma_mix_f32 %0, -%1, %2, 0 op_sel:[1,0,0] op_sel_hi:[1,0,0]"
      : "=v"(d) : "v"(g), "v"(b));
  return d;
}
// d = f16lo(g) * b + acc   (c*b + acc)
__device__ __forceinline__ float mix_c_acc(uint32_t g, float b, float acc) {
  float d;
  asm("v_fma_mix_f32 %0, %1, %2, %3 op_sel:[0,0,0] op_sel_hi:[1,0,0]"
      : "=v"(d) : "v"(g), "v"(b), "v"(acc));
  return d;
}
__device__ __forceinline__ void gate_mix(float& a, float& b, uint32_t g) {
  float t = mix_s(g, b);
  float u = mix_ns(g, a);
  float na = mix_c_acc(g, a, t);
  float nb = mix_c_acc(g, b, u);
  a = na;
  b = nb;
}

// One layer pair on an 8-wire-per-lane strip. CSHL/CSHR: DPP ctrl for
// lane i<-i+1 / lane i<-i-1 within the group (row_shl/row_shr = 16-lane rows).
template <int CSHL, int CSHR>
__device__ __forceinline__ void pair_compute(float& v0, float& v1, float& v2,
                                             float& v3, float& v4, float& v5,
                                             float& v6, float& v7,
                                             const uint4& E, const uint4& O) {
  gate_mix(v0, v1, E.x);
  gate_mix(v2, v3, E.y);
  gate_mix(v4, v5, E.z);
  gate_mix(v6, v7, E.w);
  uint32_t bl = dpp_u<CSHR>(O.w);   // left neighbor's boundary gate
  float rv0 = dpp_f<CSHL>(v0);      // right neighbor's first wire (post-even)
  float lv7 = dpp_f<CSHR>(v7);      // left neighbor's last wire (post-even)
  gate_mix(v1, v2, O.x);
  gate_mix(v3, v4, O.y);
  gate_mix(v5, v6, O.z);
  float t = mix_s(O.w, rv0);        // up-gate a-side, c = 1 + c'
  t = mix_c_acc(O.w, v7, t);
  v7 = t + v7;
  float u = mix_ns(bl, lv7);        // down-gate b-side, c = 1 + c'
  u = mix_c_acc(bl, v0, u);
  v0 = u + v0;
}

// ---------------- kernel 2: window matrices (banded rows via light-cone) ----
// Block = 1 wave = 4 groups of 16 lanes; group = (window w, basis row d).
// Group strip: wires [base, base+128), base = clamp((d-58) & ~7, 0, 384).
// Support stays within d +- 57 strictly inside the strip, so row-edge DPP
// zero-fill and untouched edge gates are exactly consistent with the circuit.
// Output: VT[w][c][d] (f16, transposed) for c in tiles floor(d/64) +- 1
// (strip values where covered, zeros elsewhere in that needed range).
__global__ __launch_bounds__(64) void window_kernel(
    const uint32_t* __restrict__ W, _Float16* __restrict__ VT) {
  const int lane = threadIdx.x;
  const int gl = lane & 15, grp = lane >> 4;
  const int w = blockIdx.x >> 7;                    // 9 windows x 128 blocks
  const int d = ((blockIdx.x & 127) << 2) + grp;    // basis row 0..511
  int b0 = d - 58;
  int base = (b0 <= 0) ? 0 : (b0 & ~7);
  base = min(base, 384);
  const int idx0 = (base >> 3) + gl;                // table lane of this slot
  const int wire0 = base + 8 * gl;

  float v0 = (wire0 + 0 == d) ? 1.f : 0.f;
  float v1 = (wire0 + 1 == d) ? 1.f : 0.f;
  float v2 = (wire0 + 2 == d) ? 1.f : 0.f;
  float v3 = (wire0 + 3 == d) ? 1.f : 0.f;
  float v4 = (wire0 + 4 == d) ? 1.f : 0.f;
  float v5 = (wire0 + 5 == d) ? 1.f : 0.f;
  float v6 = (wire0 + 6 == d) ? 1.f : 0.f;
  float v7 = (wire0 + 7 == d) ? 1.f : 0.f;

  const int p0 = w * WPAIRS;
  const int p1 = min(PAIRS, p0 + WPAIRS);
  const uint4* __restrict__ Wg = (const uint4*)W;

  uint4 R[4][2];
#pragma unroll
  for (int s0 = 0; s0 < 4; ++s0) {
    int p = min(p0 + s0, p1 - 1);
    R[s0][0] = Wg[p * 128 + idx0];
    R[s0][1] = Wg[p * 128 + 64 + idx0];
  }
  for (int p = p0; p < p1; ++p) {
    int s = (p - p0) & 3;
    wait_vm<6>();                    // oldest pair's 2 loads retired
    pair_compute<0x101, 0x111>(v0, v1, v2, v3, v4, v5, v6, v7, R[s][0], R[s][1]);
    int pn = min(p + 4, p1 - 1);     // tail: clamped reloads keep count even
    R[s][0] = Wg[pn * 128 + idx0];
    R[s][1] = Wg[pn * 128 + 64 + idx0];
  }

  _Float16* vtw = VT + (size_t)w * VT_ELEMS + d;    // column d, stride 512
  const int q = d >> 6;
  const int c0 = max(0, q - 1) << 6;
  const int c1 = (min(7, q + 1) << 6) + 64;         // exclusive
  vtw[(size_t)(wire0 + 0) * 512] = (_Float16)v0;
  vtw[(size_t)(wire0 + 1) * 512] = (_Float16)v1;
  vtw[(size_t)(wire0 + 2) * 512] = (_Float16)v2;
  vtw[(size_t)(wire0 + 3) * 512] = (_Float16)v3;
  vtw[(size_t)(wire0 + 4) * 512] = (_Float16)v4;
  vtw[(size_t)(wire0 + 5) * 512] = (_Float16)v5;
  vtw[(size_t)(wire0 + 6) * 512] = (_Float16)v6;
  vtw[(size_t)(wire0 + 7) * 512] = (_Float16)v7;
  for (int c = c0 + gl; c < base; c += 16)          // zero prefix
    vtw[(size_t)c * 512] = (_Float16)0.f;
  for (int c = base + 128 + gl; c < c1; c += 16)    // zero suffix
    vtw[(size_t)c * 512] = (_Float16)0.f;
}

// ---------------- kernel 3: banded-GEMM chain on matrix cores ---------------
// Block = 16 batch rows, 4 waves; state f32 in LDS ping-pong (pad 516 words
// -> 2-way banks). Wave wv owns col-tiles n = 2wv, 2wv+1; per tile K-blocks
// kb = n-1..n+1 (clamped). A = state rows (M=16), B = VT[w] (K=d, N=c).
// A/B share the identical lane->k map, so k-order is self-consistent.
__global__ __launch_bounds__(256, 1) void apply_kernel(
    const float* __restrict__ x, const _Float16* __restrict__ VT,
    const float* __restrict__ bias, float* __restrict__ out) {
  __shared__ float S0[16 * 516];
  __shared__ float S1[16 * 516];
  const int tid = threadIdx.x;
  const int lane = tid & 63;
  const int wv = tid >> 6;
  const int r16 = lane & 15;
  const int h = lane >> 4;
  const float* xb = x + blockIdx.x * (16 * 512);

#pragma unroll
  for (int i = 0; i < 8; ++i) {
    int e = tid + i * 256;                 // 2048 float4s of the 16x512 tile
    int r = e >> 7, cq = e & 127;
    float4 t = ((const float4*)xb)[e];
    *(float4*)&S0[r * 516 + cq * 4] = t;
  }
  __syncthreads();

  for (int w = 0; w < NWIN; ++w) {
    const float* cur = (w & 1) ? S1 : S0;
    float* nxt = (w & 1) ? S0 : S1;
    const _Float16* vtw = VT + (size_t)w * VT_ELEMS;
#pragma unroll
    for (int ti = 0; ti < 2; ++ti) {
      const int n = wv * 2 + ti;
      f32x4_t acc0 = {0.f, 0.f, 0.f, 0.f};
      f32x4_t acc1 = acc0, acc2 = acc0, acc3 = acc0;
#pragma unroll
      for (int kbr = 0; kbr < 3; ++kbr) {
        const int kb = n + kbr - 1;
        if (kb >= 0 && kb <= 7) {
#pragma unroll
          for (int ks = 0; ks < 2; ++ks) {
            const int koff = kb * 64 + ks * 32 + h * 8;
            const float* ap = cur + r16 * 516 + koff;
            float4 a0 = *(const float4*)(ap);
            float4 a1 = *(const float4*)(ap + 4);
            half8_t af;
            af[0] = (_Float16)a0.x; af[1] = (_Float16)a0.y;
            af[2] = (_Float16)a0.z; af[3] = (_Float16)a0.w;
            af[4] = (_Float16)a1.x; af[5] = (_Float16)a1.y;
            af[6] = (_Float16)a1.z; af[7] = (_Float16)a1.w;
            const _Float16* bp = vtw + (size_t)(n * 64 + r16) * 512 + koff;
            half8_t b0 = *(const half8_t*)(bp);
            half8_t b1 = *(const half8_t*)(bp + (size_t)16 * 512);
            half8_t b2 = *(const half8_t*)(bp + (size_t)32 * 512);
            half8_t b3 = *(const half8_t*)(bp + (size_t)48 * 512);
            acc0 = __builtin_amdgcn_mfma_f32_16x16x32_f16(af, b0, acc0, 0, 0, 0);
            acc1 = __builtin_amdgcn_mfma_f32_16x16x32_f16(af, b1, acc1, 0, 0, 0);
            acc2 = __builtin_amdgcn_mfma_f32_16x16x32_f16(af, b2, acc2, 0, 0, 0);
            acc3 = __builtin_amdgcn_mfma_f32_16x16x32_f16(af, b3, acc3, 0, 0, 0);
          }
        }
      }
      const int cb = n * 64 + r16;          // C/D: col = lane&15, row = 4h+j
#pragma unroll
      for (int jj = 0; jj < 4; ++jj) {
        nxt[(4 * h + jj) * 516 + cb + 0]  = acc0[jj];
        nxt[(4 * h + jj) * 516 + cb + 16] = acc1[jj];
        nxt[(4 * h + jj) * 516 + cb + 32] = acc2[jj];
        nxt[(4 * h + jj) * 516 + cb + 48] = acc3[jj];
      }
    }
    __syncthreads();
  }

  // NWIN=9: final state in S1 (w=8 even -> wrote S1)
  float* ob = out + blockIdx.x * (16 * 512);
#pragma unroll
  for (int i = 0; i < 8; ++i) {
    int e = tid + i * 256;
    int r = e >> 7, cq = e & 127;
    float4 t = *(const float4*)&S1[r * 516 + cq * 4];
    float4 bv = ((const float4*)bias)[cq];
    float4 o = {t.x + bv.x, t.y + bv.y, t.z + bv.z, t.w + bv.w};
    ((float4*)ob)[e] = o;
  }
}

extern "C" void kernel_launch(void* const* d_in, const int* in_sizes, int n_in,
                              void* d_out, int out_size, void* d_ws,
                              size_t ws_size, hipStream_t stream) {
  const float* x = (const float*)d_in[0];       // (256, 512) f32
  const float* thetas = (const float*)d_in[1];  // (130816,) f32
  const float* bias = (const float*)d_in[2];    // (512,) f32
  float* out = (float*)d_out;                   // (256, 512) f32

  uint32_t* W = (uint32_t*)d_ws;                              // 1,046,528 B
  _Float16* VT = (_Float16*)((char*)d_ws + VT_OFF_BYTES);     // 4,718,592 B

  fused_kernel<<<TOTALH2 / 256, 256, 0, stream>>>(thetas, (__half2*)W);
  window_kernel<<<NWIN * 128, 64, 0, stream>>>((const uint32_t*)W, VT);
  apply_kernel<<<16, 256, 0, stream>>>(x, VT, bias, out);
}

// Round 4
// 136.374 us; speedup vs baseline: 1.0407x; 1.0407x over previous
//
#include <hip/hip_runtime.h>
#include <hip/hip_fp16.h>
#include <stdint.h>

// OrthogonalLinear: pyramid Givens circuit, n = m = 512, B = 256, T = 1021.
// Layer t: gates (i,i+1), i = (t&1), (t&1)+2, ..., i <= min(t, 1020-t).
// theta idx: k = (t+i)/2 + 1, idx = k(k-1)/2 + (k-1-i).
//
// R14: matrix-side composition. 511 layer-pairs -> 8 windows of <=64 pairs.
//  - window_kernel: evolve basis rows over 128-wire strips (light-cone +
//    f16-decay truncation, proven in R13) with the R12 pair machinery.
//    Even windows forward -> V_w rows; odd windows BACKWARD with transposed
//    gates (reverse layer order, s -> -s; exact element-wise transpose) ->
//    V_w^T rows. All writes coalesced row-major (bpermute lane realign).
//  - gemm512: P0=V0*V1 (as PT-math -> P0 rows), P1=V2*V3 (-> P1^T rows),
//    P2, P3 likewise; then Q0=P0*P1 (-> Q0^T), Q1=P2*P3 (-> Q1^T).
//    Every GEMM: A = row-storage of left-math (contig), B = col-storage of
//    right-math (contig), C/D written col-major (lane-natural, contig).
//  - apply1: y^T = Q0^T x^T (writes y row-major f16); apply2:
//    out^T = Q1^T y^T + bias (writes out row-major f32). 64 blocks each.
// All fragment loads 16 B contiguous; no LDS; ring-3 register prefetch.

#define PAIRS 511
#define TOTALH2 (PAIRS * 512)
#define NWIN 8
#define WPAIRS 64
#define V_ELEMS (512 * 512)

#define OFF_V_BYTES (1u << 20)                      // gate table: 1,046,528 B
#define V_BYTES (512u * 512u * 2u)                  // 524,288 B per matrix
#define OFF_P_BYTES (OFF_V_BYTES + 8u * V_BYTES)    // 5 MiB
#define OFF_Q_BYTES (OFF_P_BYTES + 4u * V_BYTES)    // 7 MiB
#define OFF_Y_BYTES (OFF_Q_BYTES + 2u * V_BYTES)    // 8 MiB (y: 256 KiB)

typedef _Float16 half8_t __attribute__((ext_vector_type(8)));
typedef _Float16 half2_t __attribute__((ext_vector_type(2)));
typedef float f32x4_t __attribute__((ext_vector_type(4)));

// ---------------- kernel 1: f16 gate table (R13, unchanged, proven) --------
__global__ __launch_bounds__(256) void fused_kernel(
    const float* __restrict__ thetas, __half2* __restrict__ Wh) {
  int tid = blockIdx.x * 256 + threadIdx.x;   // exact grid: 511*512
  int p = tid >> 9, r = tid & 511;
  int h = r >> 8, rr = r & 255, L = rr >> 2, j = rr & 3;
  int t = 2 * p + h;
  int i = 8 * L + 2 * j + h;
  float c = 1.0f, s = 0.0f;
  if (i <= min(t, 1020 - t)) {
    int k = ((t + i) >> 1) + 1;
    int idx = ((k * (k - 1)) >> 1) + (k - 1 - i);
    __sincosf(thetas[idx], &s, &c);
  }
  if (h == 1 && j == 3) c -= 1.0f;   // boundary gate stored as (c-1, s)
  Wh[tid] = __floats2half2_rn(c, s);
}

// ---------------- shared device helpers (R12/R13-proven) --------------------
template <int N>
__device__ __forceinline__ void wait_vm() {
  asm volatile("s_waitcnt vmcnt(%0)" ::"i"(N) : "memory");
}
template <int CTRL>
__device__ __forceinline__ float dpp_f(float v) {
  return __int_as_float(
      __builtin_amdgcn_mov_dpp(__float_as_int(v), CTRL, 0xF, 0xF, true));
}
template <int CTRL>
__device__ __forceinline__ uint32_t dpp_u(uint32_t v) {
  return (uint32_t)__builtin_amdgcn_mov_dpp((int)v, CTRL, 0xF, 0xF, true);
}
__device__ __forceinline__ float mix_s(uint32_t g, float b) {   // s*b
  float d;
  asm("v_fma_mix_f32 %0, %1, %2, 0 op_sel:[1,0,0] op_sel_hi:[1,0,0]"
      : "=v"(d) : "v"(g), "v"(b));
  return d;
}
__device__ __forceinline__ float mix_ns(uint32_t g, float b) {  // -s*b
  float d;
  asm("v_fma_mix_f32 %0, -%1, %2, 0 op_sel:[1,0,0] op_sel_hi:[1,0,0]"
      : "=v"(d) : "v"(g), "v"(b));
  return d;
}
__device__ __forceinline__ float mix_c_acc(uint32_t g, float b, float acc) {
  float d;                                                      // c*b + acc
  asm("v_fma_mix_f32 %0, %1, %2, %3 op_sel:[0,0,0] op_sel_hi:[1,0,0]"
      : "=v"(d) : "v"(g), "v"(b), "v"(acc));
  return d;
}
// forward gate: a' = c*a + s*b ; b' = c*b - s*a
__device__ __forceinline__ void gate_mix(float& a, float& b, uint32_t g) {
  float t = mix_s(g, b);
  float u = mix_ns(g, a);
  float na = mix_c_acc(g, a, t);
  float nb = mix_c_acc(g, b, u);
  a = na; b = nb;
}
// transposed gate: a' = c*a - s*b ; b' = c*b + s*a
__device__ __forceinline__ void gate_mix_neg(float& a, float& b, uint32_t g) {
  float t = mix_ns(g, b);
  float u = mix_s(g, a);
  float na = mix_c_acc(g, a, t);
  float nb = mix_c_acc(g, b, u);
  a = na; b = nb;
}

// Forward layer pair on a 128-wire strip (16-lane row-DPP; R13-proven).
__device__ __forceinline__ void pair_fwd(float& v0, float& v1, float& v2,
                                         float& v3, float& v4, float& v5,
                                         float& v6, float& v7,
                                         const uint4& E, const uint4& O) {
  gate_mix(v0, v1, E.x);
  gate_mix(v2, v3, E.y);
  gate_mix(v4, v5, E.z);
  gate_mix(v6, v7, E.w);
  uint32_t bl = dpp_u<0x111>(O.w);   // left neighbor's boundary gate
  float rv0 = dpp_f<0x101>(v0);      // right neighbor's first wire (post-even)
  float lv7 = dpp_f<0x111>(v7);      // left neighbor's last wire (post-even)
  gate_mix(v1, v2, O.x);
  gate_mix(v3, v4, O.y);
  gate_mix(v5, v6, O.z);
  float t = mix_s(O.w, rv0);         // up-gate a-side, c = 1 + c'
  t = mix_c_acc(O.w, v7, t);
  v7 = t + v7;
  float u = mix_ns(bl, lv7);         // down-gate b-side
  u = mix_c_acc(bl, v0, u);
  v0 = u + v0;
}

// Reverse (transposed) layer pair: odd layer first, all gates with s -> -s.
__device__ __forceinline__ void pair_rev(float& v0, float& v1, float& v2,
                                         float& v3, float& v4, float& v5,
                                         float& v6, float& v7,
                                         const uint4& E, const uint4& O) {
  uint32_t bl = dpp_u<0x111>(O.w);
  float rv0 = dpp_f<0x101>(v0);      // halo on pre-layer values
  float lv7 = dpp_f<0x111>(v7);
  gate_mix_neg(v1, v2, O.x);
  gate_mix_neg(v3, v4, O.y);
  gate_mix_neg(v5, v6, O.z);
  float t = mix_ns(O.w, rv0);        // up-gate a-side transposed
  t = mix_c_acc(O.w, v7, t);
  v7 = t + v7;
  float u = mix_s(bl, lv7);          // down-gate b-side transposed
  u = mix_c_acc(bl, v0, u);
  v0 = u + v0;
  gate_mix_neg(v0, v1, E.x);
  gate_mix_neg(v2, v3, E.y);
  gate_mix_neg(v4, v5, E.z);
  gate_mix_neg(v6, v7, E.w);
}

// ---------------- kernel 2: window matrices -------------------------------
// Block = 1 wave = 4 groups of 16 lanes; group = basis row d of window w.
// Even w: forward -> row d of V_w.  Odd w: backward transposed -> row d of
// V_w^T.  Both written ROW-major (full 512 cols, zeros outside strip) via
// bpermute lane realignment -> 16-B coalesced stores.
__global__ __launch_bounds__(64) void window_kernel(
    const uint32_t* __restrict__ W, _Float16* __restrict__ V) {
  const int lane = threadIdx.x;
  const int gl = lane & 15, grp = lane >> 4;
  const int w = blockIdx.x >> 7;                    // 8 windows x 128 blocks
  const int d = ((blockIdx.x & 127) << 2) + grp;    // basis row 0..511
  const bool rev = (w & 1);
  int b0 = d - 60;
  int base = (b0 <= 0) ? 0 : (b0 & ~7);
  base = min(base, 384);
  const int idx0 = (base >> 3) + gl;
  const int wire0 = base + 8 * gl;

  float v0 = (wire0 + 0 == d) ? 1.f : 0.f;
  float v1 = (wire0 + 1 == d) ? 1.f : 0.f;
  float v2 = (wire0 + 2 == d) ? 1.f : 0.f;
  float v3 = (wire0 + 3 == d) ? 1.f : 0.f;
  float v4 = (wire0 + 4 == d) ? 1.f : 0.f;
  float v5 = (wire0 + 5 == d) ? 1.f : 0.f;
  float v6 = (wire0 + 6 == d) ? 1.f : 0.f;
  float v7 = (wire0 + 7 == d) ? 1.f : 0.f;

  const int p0 = w * WPAIRS;
  const int p1 = min(PAIRS, p0 + WPAIRS);
  const int np = p1 - p0;
  const uint4* __restrict__ Wg = (const uint4*)W;

  uint4 R[4][2];
#pragma unroll
  for (int s0 = 0; s0 < 4; ++s0) {
    int p = rev ? max(p1 - 1 - s0, p0) : min(p0 + s0, p1 - 1);
    R[s0][0] = Wg[p * 128 + idx0];
    R[s0][1] = Wg[p * 128 + 64 + idx0];
  }
  for (int step = 0; step < np; ++step) {
    const int s = step & 3;
    wait_vm<6>();
    if (rev)
      pair_rev(v0, v1, v2, v3, v4, v5, v6, v7, R[s][0], R[s][1]);
    else
      pair_fwd(v0, v1, v2, v3, v4, v5, v6, v7, R[s][0], R[s][1]);
    int pn = rev ? max(p1 - 1 - (step + 4), p0) : min(p0 + step + 4, p1 - 1);
    R[s][0] = Wg[pn * 128 + idx0];
    R[s][1] = Wg[pn * 128 + 64 + idx0];
  }

  // pack f32 -> f16 pairs, realign lanes per 128-col pass, coalesced store
  uint32_t ph0 = __builtin_bit_cast(uint32_t, __builtin_amdgcn_cvt_pkrtz(v0, v1));
  uint32_t ph1 = __builtin_bit_cast(uint32_t, __builtin_amdgcn_cvt_pkrtz(v2, v3));
  uint32_t ph2 = __builtin_bit_cast(uint32_t, __builtin_amdgcn_cvt_pkrtz(v4, v5));
  uint32_t ph3 = __builtin_bit_cast(uint32_t, __builtin_amdgcn_cvt_pkrtz(v6, v7));
  uint32_t* dst =
      (uint32_t*)(V + (size_t)w * V_ELEMS + (size_t)d * 512);
#pragma unroll
  for (int pass = 0; pass < 4; ++pass) {
    const int S = ((pass << 7) - base) >> 3;
    const int srcg = gl + S;
    const bool ok = (srcg >= 0) && (srcg < 16);
    const int baddr = ((grp << 4) + (ok ? srcg : 0)) << 2;
    uint32_t o0 = (uint32_t)__builtin_amdgcn_ds_bpermute(baddr, (int)ph0);
    uint32_t o1 = (uint32_t)__builtin_amdgcn_ds_bpermute(baddr, (int)ph1);
    uint32_t o2 = (uint32_t)__builtin_amdgcn_ds_bpermute(baddr, (int)ph2);
    uint32_t o3 = (uint32_t)__builtin_amdgcn_ds_bpermute(baddr, (int)ph3);
    if (!ok) { o0 = 0u; o1 = 0u; o2 = 0u; o3 = 0u; }
    *(uint4*)(dst + pass * 64 + gl * 4) = make_uint4(o0, o1, o2, o3);
  }
}

// ---------------- kernel 3: generic 512^3 f16 GEMM on matrix cores ---------
// math D = A_math * B_math.  A = row-storage of A_math; B = col-storage of
// B_math (i.e. rows of B_math^T); C written as col-storage of D.  Block =
// 128 thr = 2 waves, tile 32x64; grid = ngemm*128 (16 rowtiles x 8 coltiles).
struct GemmDesc { const _Float16* A; const _Float16* B; _Float16* C; };
struct Descs4 { GemmDesc d[4]; };

__global__ __launch_bounds__(128) void gemm512_kernel(Descs4 ds) {
  const int g = blockIdx.x >> 7;
  const int t = blockIdx.x & 127;
  const int rt = t >> 3, ct = t & 7;
  const int lane = threadIdx.x & 63, wv = threadIdx.x >> 6;
  const int l16 = lane & 15, h8 = (lane >> 4) * 8;
  const GemmDesc de = ds.d[g];
  const _Float16* Ap = de.A + (size_t)(rt * 32 + wv * 16 + l16) * 512 + h8;
  const _Float16* Bp = de.B + (size_t)(ct * 64 + l16) * 512 + h8;

  half8_t aR[3]; half8_t bR[3][4];
#pragma unroll
  for (int s = 0; s < 3; ++s) {
    aR[s] = *(const half8_t*)(Ap + s * 32);
#pragma unroll
    for (int n = 0; n < 4; ++n)
      bR[s][n] = *(const half8_t*)(Bp + (size_t)n * (16 * 512) + s * 32);
  }
  f32x4_t acc[4];
#pragma unroll
  for (int n = 0; n < 4; ++n) acc[n] = (f32x4_t){0.f, 0.f, 0.f, 0.f};

#pragma unroll
  for (int ks = 0; ks < 16; ++ks) {
    const int s = ks % 3;
    if (ks <= 13) wait_vm<10>();
    else if (ks == 14) wait_vm<5>();
    else wait_vm<0>();
    half8_t a = aR[s];
    half8_t b0 = bR[s][0], b1 = bR[s][1], b2 = bR[s][2], b3 = bR[s][3];
    if (ks + 3 < 16) {
      aR[s] = *(const half8_t*)(Ap + (ks + 3) * 32);
#pragma unroll
      for (int n = 0; n < 4; ++n)
        bR[s][n] = *(const half8_t*)(Bp + (size_t)n * (16 * 512) + (ks + 3) * 32);
    }
    acc[0] = __builtin_amdgcn_mfma_f32_16x16x32_f16(a, b0, acc[0], 0, 0, 0);
    acc[1] = __builtin_amdgcn_mfma_f32_16x16x32_f16(a, b1, acc[1], 0, 0, 0);
    acc[2] = __builtin_amdgcn_mfma_f32_16x16x32_f16(a, b2, acc[2], 0, 0, 0);
    acc[3] = __builtin_amdgcn_mfma_f32_16x16x32_f16(a, b3, acc[3], 0, 0, 0);
  }
  const int r4 = rt * 32 + wv * 16 + (lane >> 4) * 4;   // C/D rows
#pragma unroll
  for (int n = 0; n < 4; ++n) {
    uint2 pk;
    pk.x = __builtin_bit_cast(uint32_t,
             __builtin_amdgcn_cvt_pkrtz(acc[n][0], acc[n][1]));
    pk.y = __builtin_bit_cast(uint32_t,
             __builtin_amdgcn_cvt_pkrtz(acc[n][2], acc[n][3]));
    *(uint2*)(de.C + (size_t)(ct * 64 + n * 16 + l16) * 512 + r4) = pk;
  }
}

// ---------------- kernel 4: apply1, y^T = Q0^T x^T (x is f32) --------------
__global__ __launch_bounds__(128) void apply1_kernel(
    const _Float16* __restrict__ Qt0, const float* __restrict__ x,
    _Float16* __restrict__ y) {
  const int rt = blockIdx.x >> 2, ct = blockIdx.x & 3;   // 16 x 4
  const int lane = threadIdx.x & 63, wv = threadIdx.x >> 6;
  const int l16 = lane & 15, h8 = (lane >> 4) * 8;
  const _Float16* Ap = Qt0 + (size_t)(rt * 32 + wv * 16 + l16) * 512 + h8;
  const float* Bx = x + (size_t)(ct * 64 + l16) * 512 + h8;

  half8_t aR[2]; float4 fR[2][4][2];
#pragma unroll
  for (int s = 0; s < 2; ++s) {
    aR[s] = *(const half8_t*)(Ap + s * 32);
#pragma unroll
    for (int n = 0; n < 4; ++n) {
      fR[s][n][0] = *(const float4*)(Bx + (size_t)n * (16 * 512) + s * 32);
      fR[s][n][1] = *(const float4*)(Bx + (size_t)n * (16 * 512) + s * 32 + 4);
    }
  }
  f32x4_t acc[4];
#pragma unroll
  for (int n = 0; n < 4; ++n) acc[n] = (f32x4_t){0.f, 0.f, 0.f, 0.f};

#pragma unroll
  for (int ks = 0; ks < 16; ++ks) {
    const int s = ks & 1;
    if (ks <= 14) wait_vm<9>();
    else wait_vm<0>();
    half8_t a = aR[s];
    half8_t bf[4];
#pragma unroll
    for (int n = 0; n < 4; ++n) {
      float4 f0 = fR[s][n][0], f1 = fR[s][n][1];
      uint4 u;
      u.x = __builtin_bit_cast(uint32_t, __builtin_amdgcn_cvt_pkrtz(f0.x, f0.y));
      u.y = __builtin_bit_cast(uint32_t, __builtin_amdgcn_cvt_pkrtz(f0.z, f0.w));
      u.z = __builtin_bit_cast(uint32_t, __builtin_amdgcn_cvt_pkrtz(f1.x, f1.y));
      u.w = __builtin_bit_cast(uint32_t, __builtin_amdgcn_cvt_pkrtz(f1.z, f1.w));
      bf[n] = __builtin_bit_cast(half8_t, u);
    }
    if (ks + 2 < 16) {
      aR[s] = *(const half8_t*)(Ap + (ks + 2) * 32);
#pragma unroll
      for (int n = 0; n < 4; ++n) {
        fR[s][n][0] = *(const float4*)(Bx + (size_t)n * (16 * 512) + (ks + 2) * 32);
        fR[s][n][1] = *(const float4*)(Bx + (size_t)n * (16 * 512) + (ks + 2) * 32 + 4);
      }
    }
    acc[0] = __builtin_amdgcn_mfma_f32_16x16x32_f16(a, bf[0], acc[0], 0, 0, 0);
    acc[1] = __builtin_amdgcn_mfma_f32_16x16x32_f16(a, bf[1], acc[1], 0, 0, 0);
    acc[2] = __builtin_amdgcn_mfma_f32_16x16x32_f16(a, bf[2], acc[2], 0, 0, 0);
    acc[3] = __builtin_amdgcn_mfma_f32_16x16x32_f16(a, bf[3], acc[3], 0, 0, 0);
  }
  const int r4 = rt * 32 + wv * 16 + (lane >> 4) * 4;
#pragma unroll
  for (int n = 0; n < 4; ++n) {
    uint2 pk;
    pk.x = __builtin_bit_cast(uint32_t,
             __builtin_amdgcn_cvt_pkrtz(acc[n][0], acc[n][1]));
    pk.y = __builtin_bit_cast(uint32_t,
             __builtin_amdgcn_cvt_pkrtz(acc[n][2], acc[n][3]));
    *(uint2*)(y + (size_t)(ct * 64 + n * 16 + l16) * 512 + r4) = pk;
  }
}

// ---------------- kernel 5: apply2, out^T = Q1^T y^T, +bias, f32 out -------
__global__ __launch_bounds__(128) void apply2_kernel(
    const _Float16* __restrict__ Qt1, const _Float16* __restrict__ y,
    const float* __restrict__ bias, float* __restrict__ out) {
  const int rt = blockIdx.x >> 2, ct = blockIdx.x & 3;
  const int lane = threadIdx.x & 63, wv = threadIdx.x >> 6;
  const int l16 = lane & 15, h8 = (lane >> 4) * 8;
  const _Float16* Ap = Qt1 + (size_t)(rt * 32 + wv * 16 + l16) * 512 + h8;
  const _Float16* Bp = y + (size_t)(ct * 64 + l16) * 512 + h8;

  half8_t aR[3]; half8_t bR[3][4];
#pragma unroll
  for (int s = 0; s < 3; ++s) {
    aR[s] = *(const half8_t*)(Ap + s * 32);
#pragma unroll
    for (int n = 0; n < 4; ++n)
      bR[s][n] = *(const half8_t*)(Bp + (size_t)n * (16 * 512) + s * 32);
  }
  f32x4_t acc[4];
#pragma unroll
  for (int n = 0; n < 4; ++n) acc[n] = (f32x4_t){0.f, 0.f, 0.f, 0.f};

#pragma unroll
  for (int ks = 0; ks < 16; ++ks) {
    const int s = ks % 3;
    if (ks <= 13) wait_vm<10>();
    else if (ks == 14) wait_vm<5>();
    else wait_vm<0>();
    half8_t a = aR[s];
    half8_t b0 = bR[s][0], b1 = bR[s][1], b2 = bR[s][2], b3 = bR[s][3];
    if (ks + 3 < 16) {
      aR[s] = *(const half8_t*)(Ap + (ks + 3) * 32);
#pragma unroll
      for (int n = 0; n < 4; ++n)
        bR[s][n] = *(const half8_t*)(Bp + (size_t)n * (16 * 512) + (ks + 3) * 32);
    }
    acc[0] = __builtin_amdgcn_mfma_f32_16x16x32_f16(a, b0, acc[0], 0, 0, 0);
    acc[1] = __builtin_amdgcn_mfma_f32_16x16x32_f16(a, b1, acc[1], 0, 0, 0);
    acc[2] = __builtin_amdgcn_mfma_f32_16x16x32_f16(a, b2, acc[2], 0, 0, 0);
    acc[3] = __builtin_amdgcn_mfma_f32_16x16x32_f16(a, b3, acc[3], 0, 0, 0);
  }
  const int r4 = rt * 32 + wv * 16 + (lane >> 4) * 4;    // out wire c base
  const float4 bv = *(const float4*)(bias + r4);
#pragma unroll
  for (int n = 0; n < 4; ++n) {
    const int b = ct * 64 + n * 16 + l16;                // batch row
    float4 o;
    o.x = acc[n][0] + bv.x;
    o.y = acc[n][1] + bv.y;
    o.z = acc[n][2] + bv.z;
    o.w = acc[n][3] + bv.w;
    *(float4*)(out + (size_t)b * 512 + r4) = o;
  }
}

extern "C" void kernel_launch(void* const* d_in, const int* in_sizes, int n_in,
                              void* d_out, int out_size, void* d_ws,
                              size_t ws_size, hipStream_t stream) {
  const float* x = (const float*)d_in[0];       // (256, 512) f32
  const float* thetas = (const float*)d_in[1];  // (130816,) f32
  const float* bias = (const float*)d_in[2];    // (512,) f32
  float* out = (float*)d_out;                   // (256, 512) f32

  char* ws = (char*)d_ws;                       // uses 8.25 MiB
  uint32_t* W = (uint32_t*)ws;
  _Float16* V = (_Float16*)(ws + OFF_V_BYTES);
  _Float16* P = (_Float16*)(ws + OFF_P_BYTES);
  _Float16* Q = (_Float16*)(ws + OFF_Q_BYTES);
  _Float16* Y = (_Float16*)(ws + OFF_Y_BYTES);

  fused_kernel<<<TOTALH2 / 256, 256, 0, stream>>>(thetas, (__half2*)W);
  window_kernel<<<NWIN * 128, 64, 0, stream>>>(W, V);

  // L1: P0 = V0*V1 (math P0^T -> P0 rows), P1 = V2*V3 (math P1 -> P1^T rows),
  //     P2 = V4*V5 (-> rows), P3 = V6*V7 (-> ^T rows).
  Descs4 l1;
  l1.d[0] = {V + 1 * (size_t)V_ELEMS, V + 0 * (size_t)V_ELEMS, P + 0 * (size_t)V_ELEMS};
  l1.d[1] = {V + 2 * (size_t)V_ELEMS, V + 3 * (size_t)V_ELEMS, P + 1 * (size_t)V_ELEMS};
  l1.d[2] = {V + 5 * (size_t)V_ELEMS, V + 4 * (size_t)V_ELEMS, P + 2 * (size_t)V_ELEMS};
  l1.d[3] = {V + 6 * (size_t)V_ELEMS, V + 7 * (size_t)V_ELEMS, P + 3 * (size_t)V_ELEMS};
  gemm512_kernel<<<512, 128, 0, stream>>>(l1);

  // L2: Q0 = P0*P1 -> Q0^T rows; Q1 = P2*P3 -> Q1^T rows.
  Descs4 l2;
  l2.d[0] = {P + 0 * (size_t)V_ELEMS, P + 1 * (size_t)V_ELEMS, Q + 0 * (size_t)V_ELEMS};
  l2.d[1] = {P + 2 * (size_t)V_ELEMS, P + 3 * (size_t)V_ELEMS, Q + 1 * (size_t)V_ELEMS};
  l2.d[2] = l2.d[0];
  l2.d[3] = l2.d[0];
  gemm512_kernel<<<256, 128, 0, stream>>>(l2);

  apply1_kernel<<<64, 128, 0, stream>>>(Q + 0 * (size_t)V_ELEMS, x, Y);
  apply2_kernel<<<64, 128, 0, stream>>>(Q + 1 * (size_t)V_ELEMS, Y, bias, out);
}

// Round 5
// 107.348 us; speedup vs baseline: 1.3221x; 1.2704x over previous
//
#include <hip/hip_runtime.h>
#include <hip/hip_fp16.h>
#include <stdint.h>

// OrthogonalLinear: pyramid Givens circuit, n = m = 512, B = 256, T = 1021.
// Layer t: gates (i,i+1), i = (t&1), (t&1)+2, ..., i <= min(t, 1020-t).
// theta idx: k = (t+i)/2 + 1, idx = k(k-1)/2 + (k-1-i).
//
// R15 = R14 (matrix-side composition, proven correct) with window_kernel's
// scratch-spill bug fixed: R14's `R[step & 3]` runtime index sent the ring
// to scratch (VGPR_Count=24, 4 scratch vmem ops/pair on the critical path,
// 44 us). Now: gate table padded to 512 pairs (pair 511 = identity via the
// existing validity test) so every window is exactly 64 pairs, and the loop
// is outer x16 / inner `#pragma unroll` x4 with compile-time ring index --
// the R10/R12-proven pattern. fwd/rev variants are separate loops.
//
// Pipeline: fused_kernel (gate table) -> window_kernel (8 window matrices,
// even fwd -> V rows, odd backward-transposed -> V^T rows, all writes
// coalesced) -> gemm512 x2 levels (P = V*V, Q = P*P; alternating
// orientation so every operand is contiguous) -> apply1 (y^T = Q0^T x^T)
// -> apply2 (out^T = Q1^T y^T + bias).

#define PAIRS_PAD 512
#define TOTALH2 (PAIRS_PAD * 512)
#define NWIN 8
#define WPAIRS 64
#define V_ELEMS (512 * 512)

#define OFF_V_BYTES (1u << 20)                      // gate table: exactly 1 MiB
#define V_BYTES (512u * 512u * 2u)                  // 524,288 B per matrix
#define OFF_P_BYTES (OFF_V_BYTES + 8u * V_BYTES)    // 5 MiB
#define OFF_Q_BYTES (OFF_P_BYTES + 4u * V_BYTES)    // 7 MiB
#define OFF_Y_BYTES (OFF_Q_BYTES + 2u * V_BYTES)    // 8 MiB (y: 256 KiB)

typedef _Float16 half8_t __attribute__((ext_vector_type(8)));
typedef float f32x4_t __attribute__((ext_vector_type(4)));

// ---------------- kernel 1: f16 gate table ---------------------------------
// uint4 idx = p*128 + h*64 + L; h=0: even-layer gates of wires 8L+{0,2,4,6};
// h=1: odd-layer gates 8L+{1,3,5}, .w = boundary gate (8L+7,8L+8) as (c-1,s).
// Dead slots identity; pairs >= 511 fall out as identity via the validity
// test (t > 1020 -> no gate valid; odd boundary becomes (0,0) = identity).
__global__ __launch_bounds__(256) void fused_kernel(
    const float* __restrict__ thetas, __half2* __restrict__ Wh) {
  int tid = blockIdx.x * 256 + threadIdx.x;   // exact grid: 512*512
  int p = tid >> 9, r = tid & 511;
  int h = r >> 8, rr = r & 255, L = rr >> 2, j = rr & 3;
  int t = 2 * p + h;
  int i = 8 * L + 2 * j + h;
  float c = 1.0f, s = 0.0f;
  if (i <= min(t, 1020 - t)) {
    int k = ((t + i) >> 1) + 1;
    int idx = ((k * (k - 1)) >> 1) + (k - 1 - i);
    __sincosf(thetas[idx], &s, &c);
  }
  if (h == 1 && j == 3) c -= 1.0f;   // boundary gate stored as (c-1, s)
  Wh[tid] = __floats2half2_rn(c, s);
}

// ---------------- shared device helpers (R12/R13-proven) --------------------
template <int N>
__device__ __forceinline__ void wait_vm() {
  asm volatile("s_waitcnt vmcnt(%0)" ::"i"(N) : "memory");
}
template <int CTRL>
__device__ __forceinline__ float dpp_f(float v) {
  return __int_as_float(
      __builtin_amdgcn_mov_dpp(__float_as_int(v), CTRL, 0xF, 0xF, true));
}
template <int CTRL>
__device__ __forceinline__ uint32_t dpp_u(uint32_t v) {
  return (uint32_t)__builtin_amdgcn_mov_dpp((int)v, CTRL, 0xF, 0xF, true);
}
__device__ __forceinline__ float mix_s(uint32_t g, float b) {   // s*b
  float d;
  asm("v_fma_mix_f32 %0, %1, %2, 0 op_sel:[1,0,0] op_sel_hi:[1,0,0]"
      : "=v"(d) : "v"(g), "v"(b));
  return d;
}
__device__ __forceinline__ float mix_ns(uint32_t g, float b) {  // -s*b
  float d;
  asm("v_fma_mix_f32 %0, -%1, %2, 0 op_sel:[1,0,0] op_sel_hi:[1,0,0]"
      : "=v"(d) : "v"(g), "v"(b));
  return d;
}
__device__ __forceinline__ float mix_c_acc(uint32_t g, float b, float acc) {
  float d;                                                      // c*b + acc
  asm("v_fma_mix_f32 %0, %1, %2, %3 op_sel:[0,0,0] op_sel_hi:[1,0,0]"
      : "=v"(d) : "v"(g), "v"(b), "v"(acc));
  return d;
}
// forward gate: a' = c*a + s*b ; b' = c*b - s*a
__device__ __forceinline__ void gate_mix(float& a, float& b, uint32_t g) {
  float t = mix_s(g, b);
  float u = mix_ns(g, a);
  float na = mix_c_acc(g, a, t);
  float nb = mix_c_acc(g, b, u);
  a = na; b = nb;
}
// transposed gate: a' = c*a - s*b ; b' = c*b + s*a
__device__ __forceinline__ void gate_mix_neg(float& a, float& b, uint32_t g) {
  float t = mix_ns(g, b);
  float u = mix_s(g, a);
  float na = mix_c_acc(g, a, t);
  float nb = mix_c_acc(g, b, u);
  a = na; b = nb;
}

// Forward layer pair on a 128-wire strip (16-lane row-DPP).
__device__ __forceinline__ void pair_fwd(float& v0, float& v1, float& v2,
                                         float& v3, float& v4, float& v5,
                                         float& v6, float& v7,
                                         const uint4& E, const uint4& O) {
  gate_mix(v0, v1, E.x);
  gate_mix(v2, v3, E.y);
  gate_mix(v4, v5, E.z);
  gate_mix(v6, v7, E.w);
  uint32_t bl = dpp_u<0x111>(O.w);   // left neighbor's boundary gate
  float rv0 = dpp_f<0x101>(v0);      // right neighbor's first wire (post-even)
  float lv7 = dpp_f<0x111>(v7);      // left neighbor's last wire (post-even)
  gate_mix(v1, v2, O.x);
  gate_mix(v3, v4, O.y);
  gate_mix(v5, v6, O.z);
  float t = mix_s(O.w, rv0);         // up-gate a-side, c = 1 + c'
  t = mix_c_acc(O.w, v7, t);
  v7 = t + v7;
  float u = mix_ns(bl, lv7);         // down-gate b-side
  u = mix_c_acc(bl, v0, u);
  v0 = u + v0;
}

// Reverse (transposed) layer pair: odd layer first, all gates with s -> -s.
__device__ __forceinline__ void pair_rev(float& v0, float& v1, float& v2,
                                         float& v3, float& v4, float& v5,
                                         float& v6, float& v7,
                                         const uint4& E, const uint4& O) {
  uint32_t bl = dpp_u<0x111>(O.w);
  float rv0 = dpp_f<0x101>(v0);      // halo on pre-layer values
  float lv7 = dpp_f<0x111>(v7);
  gate_mix_neg(v1, v2, O.x);
  gate_mix_neg(v3, v4, O.y);
  gate_mix_neg(v5, v6, O.z);
  float t = mix_ns(O.w, rv0);        // up-gate a-side transposed
  t = mix_c_acc(O.w, v7, t);
  v7 = t + v7;
  float u = mix_s(bl, lv7);          // down-gate b-side transposed
  u = mix_c_acc(bl, v0, u);
  v0 = u + v0;
  gate_mix_neg(v0, v1, E.x);
  gate_mix_neg(v2, v3, E.y);
  gate_mix_neg(v4, v5, E.z);
  gate_mix_neg(v6, v7, E.w);
}

// ---------------- kernel 2: window matrices -------------------------------
// Block = 1 wave = 4 groups of 16 lanes; group = basis row d of window w.
// Even w: forward -> row d of V_w.  Odd w: backward transposed -> row d of
// V_w^T.  Strip [base, base+128), base = clamp((d-60) & ~7, 0, 384); light-
// cone + f16 sine-product decay keeps truncation below f16 noise (R13/R14
// verified, absmax unchanged).  Ring: 4 pairs x 2 quads, COMPILE-TIME index
// (outer x16, inner unroll x4) -- R14's runtime `R[step&3]` spilled to
// scratch (VGPR=24, 44 us); this restores the R10/R12 register ring.
__global__ __launch_bounds__(64) void window_kernel(
    const uint32_t* __restrict__ W, _Float16* __restrict__ V) {
  const int lane = threadIdx.x;
  const int gl = lane & 15, grp = lane >> 4;
  const int w = blockIdx.x >> 7;                    // 8 windows x 128 blocks
  const int d = ((blockIdx.x & 127) << 2) + grp;    // basis row 0..511
  const bool rev = (w & 1);
  int b0 = d - 60;
  int base = (b0 <= 0) ? 0 : (b0 & ~7);
  base = min(base, 384);
  const int idx0 = (base >> 3) + gl;
  const int wire0 = base + 8 * gl;

  float v0 = (wire0 + 0 == d) ? 1.f : 0.f;
  float v1 = (wire0 + 1 == d) ? 1.f : 0.f;
  float v2 = (wire0 + 2 == d) ? 1.f : 0.f;
  float v3 = (wire0 + 3 == d) ? 1.f : 0.f;
  float v4 = (wire0 + 4 == d) ? 1.f : 0.f;
  float v5 = (wire0 + 5 == d) ? 1.f : 0.f;
  float v6 = (wire0 + 6 == d) ? 1.f : 0.f;
  float v7 = (wire0 + 7 == d) ? 1.f : 0.f;

  const int p0 = w * WPAIRS;                        // exactly 64 pairs/window
  const uint4* __restrict__ Wg = (const uint4*)W;

  uint4 R[4][2];
  if (!rev) {
#pragma unroll
    for (int s = 0; s < 4; ++s) {
      R[s][0] = Wg[(p0 + s) * 128 + idx0];
      R[s][1] = Wg[(p0 + s) * 128 + 64 + idx0];
    }
    for (int it = 0; it < 16; ++it) {
#pragma unroll
      for (int s = 0; s < 4; ++s) {
        wait_vm<6>();
        pair_fwd(v0, v1, v2, v3, v4, v5, v6, v7, R[s][0], R[s][1]);
        int pn = p0 + min(it * 4 + s + 4, 63);  // clamp keeps vmcnt count even
        R[s][0] = Wg[pn * 128 + idx0];
        R[s][1] = Wg[pn * 128 + 64 + idx0];
      }
    }
  } else {
#pragma unroll
    for (int s = 0; s < 4; ++s) {
      R[s][0] = Wg[(p0 + 63 - s) * 128 + idx0];
      R[s][1] = Wg[(p0 + 63 - s) * 128 + 64 + idx0];
    }
    for (int it = 0; it < 16; ++it) {
#pragma unroll
      for (int s = 0; s < 4; ++s) {
        wait_vm<6>();
        pair_rev(v0, v1, v2, v3, v4, v5, v6, v7, R[s][0], R[s][1]);
        int pn = p0 + 63 - min(it * 4 + s + 4, 63);
        R[s][0] = Wg[pn * 128 + idx0];
        R[s][1] = Wg[pn * 128 + 64 + idx0];
      }
    }
  }

  // pack f32 -> f16 pairs, realign lanes per 128-col pass, coalesced store
  uint32_t ph0 = __builtin_bit_cast(uint32_t, __builtin_amdgcn_cvt_pkrtz(v0, v1));
  uint32_t ph1 = __builtin_bit_cast(uint32_t, __builtin_amdgcn_cvt_pkrtz(v2, v3));
  uint32_t ph2 = __builtin_bit_cast(uint32_t, __builtin_amdgcn_cvt_pkrtz(v4, v5));
  uint32_t ph3 = __builtin_bit_cast(uint32_t, __builtin_amdgcn_cvt_pkrtz(v6, v7));
  uint32_t* dst = (uint32_t*)(V + (size_t)w * V_ELEMS + (size_t)d * 512);
#pragma unroll
  for (int pass = 0; pass < 4; ++pass) {
    const int S = ((pass << 7) - base) >> 3;
    const int srcg = gl + S;
    const bool ok = (srcg >= 0) && (srcg < 16);
    const int baddr = ((grp << 4) + (ok ? srcg : 0)) << 2;
    uint32_t o0 = (uint32_t)__builtin_amdgcn_ds_bpermute(baddr, (int)ph0);
    uint32_t o1 = (uint32_t)__builtin_amdgcn_ds_bpermute(baddr, (int)ph1);
    uint32_t o2 = (uint32_t)__builtin_amdgcn_ds_bpermute(baddr, (int)ph2);
    uint32_t o3 = (uint32_t)__builtin_amdgcn_ds_bpermute(baddr, (int)ph3);
    if (!ok) { o0 = 0u; o1 = 0u; o2 = 0u; o3 = 0u; }
    *(uint4*)(dst + pass * 64 + gl * 4) = make_uint4(o0, o1, o2, o3);
  }
}

// ---------------- kernel 3: generic 512^3 f16 GEMM on matrix cores ---------
// math D = A_math * B_math.  A = row-storage of A_math; B = col-storage of
// B_math; C written as col-storage of D.  Block = 128 thr = 2 waves, tile
// 32x64; grid = ngemm*128 (16 rowtiles x 8 coltiles).
struct GemmDesc { const _Float16* A; const _Float16* B; _Float16* C; };
struct Descs4 { GemmDesc d[4]; };

__global__ __launch_bounds__(128) void gemm512_kernel(Descs4 ds) {
  const int g = blockIdx.x >> 7;
  const int t = blockIdx.x & 127;
  const int rt = t >> 3, ct = t & 7;
  const int lane = threadIdx.x & 63, wv = threadIdx.x >> 6;
  const int l16 = lane & 15, h8 = (lane >> 4) * 8;
  const GemmDesc de = ds.d[g];
  const _Float16* Ap = de.A + (size_t)(rt * 32 + wv * 16 + l16) * 512 + h8;
  const _Float16* Bp = de.B + (size_t)(ct * 64 + l16) * 512 + h8;

  half8_t aR[3]; half8_t bR[3][4];
#pragma unroll
  for (int s = 0; s < 3; ++s) {
    aR[s] = *(const half8_t*)(Ap + s * 32);
#pragma unroll
    for (int n = 0; n < 4; ++n)
      bR[s][n] = *(const half8_t*)(Bp + (size_t)n * (16 * 512) + s * 32);
  }
  f32x4_t acc[4];
#pragma unroll
  for (int n = 0; n < 4; ++n) acc[n] = (f32x4_t){0.f, 0.f, 0.f, 0.f};

#pragma unroll
  for (int ks = 0; ks < 16; ++ks) {
    const int s = ks % 3;
    if (ks <= 13) wait_vm<10>();
    else if (ks == 14) wait_vm<5>();
    else wait_vm<0>();
    half8_t a = aR[s];
    half8_t b0 = bR[s][0], b1 = bR[s][1], b2 = bR[s][2], b3 = bR[s][3];
    if (ks + 3 < 16) {
      aR[s] = *(const half8_t*)(Ap + (ks + 3) * 32);
#pragma unroll
      for (int n = 0; n < 4; ++n)
        bR[s][n] = *(const half8_t*)(Bp + (size_t)n * (16 * 512) + (ks + 3) * 32);
    }
    acc[0] = __builtin_amdgcn_mfma_f32_16x16x32_f16(a, b0, acc[0], 0, 0, 0);
    acc[1] = __builtin_amdgcn_mfma_f32_16x16x32_f16(a, b1, acc[1], 0, 0, 0);
    acc[2] = __builtin_amdgcn_mfma_f32_16x16x32_f16(a, b2, acc[2], 0, 0, 0);
    acc[3] = __builtin_amdgcn_mfma_f32_16x16x32_f16(a, b3, acc[3], 0, 0, 0);
  }
  const int r4 = rt * 32 + wv * 16 + (lane >> 4) * 4;   // C/D rows
#pragma unroll
  for (int n = 0; n < 4; ++n) {
    uint2 pk;
    pk.x = __builtin_bit_cast(uint32_t,
             __builtin_amdgcn_cvt_pkrtz(acc[n][0], acc[n][1]));
    pk.y = __builtin_bit_cast(uint32_t,
             __builtin_amdgcn_cvt_pkrtz(acc[n][2], acc[n][3]));
    *(uint2*)(de.C + (size_t)(ct * 64 + n * 16 + l16) * 512 + r4) = pk;
  }
}

// ---------------- kernel 4: apply1, y^T = Q0^T x^T (x is f32) --------------
__global__ __launch_bounds__(128) void apply1_kernel(
    const _Float16* __restrict__ Qt0, const float* __restrict__ x,
    _Float16* __restrict__ y) {
  const int rt = blockIdx.x >> 2, ct = blockIdx.x & 3;   // 16 x 4
  const int lane = threadIdx.x & 63, wv = threadIdx.x >> 6;
  const int l16 = lane & 15, h8 = (lane >> 4) * 8;
  const _Float16* Ap = Qt0 + (size_t)(rt * 32 + wv * 16 + l16) * 512 + h8;
  const float* Bx = x + (size_t)(ct * 64 + l16) * 512 + h8;

  half8_t aR[2]; float4 fR[2][4][2];
#pragma unroll
  for (int s = 0; s < 2; ++s) {
    aR[s] = *(const half8_t*)(Ap + s * 32);
#pragma unroll
    for (int n = 0; n < 4; ++n) {
      fR[s][n][0] = *(const float4*)(Bx + (size_t)n * (16 * 512) + s * 32);
      fR[s][n][1] = *(const float4*)(Bx + (size_t)n * (16 * 512) + s * 32 + 4);
    }
  }
  f32x4_t acc[4];
#pragma unroll
  for (int n = 0; n < 4; ++n) acc[n] = (f32x4_t){0.f, 0.f, 0.f, 0.f};

#pragma unroll
  for (int ks = 0; ks < 16; ++ks) {
    const int s = ks & 1;
    if (ks <= 14) wait_vm<9>();
    else wait_vm<0>();
    half8_t a = aR[s];
    half8_t bf[4];
#pragma unroll
    for (int n = 0; n < 4; ++n) {
      float4 f0 = fR[s][n][0], f1 = fR[s][n][1];
      uint4 u;
      u.x = __builtin_bit_cast(uint32_t, __builtin_amdgcn_cvt_pkrtz(f0.x, f0.y));
      u.y = __builtin_bit_cast(uint32_t, __builtin_amdgcn_cvt_pkrtz(f0.z, f0.w));
      u.z = __builtin_bit_cast(uint32_t, __builtin_amdgcn_cvt_pkrtz(f1.x, f1.y));
      u.w = __builtin_bit_cast(uint32_t, __builtin_amdgcn_cvt_pkrtz(f1.z, f1.w));
      bf[n] = __builtin_bit_cast(half8_t, u);
    }
    if (ks + 2 < 16) {
      aR[s] = *(const half8_t*)(Ap + (ks + 2) * 32);
#pragma unroll
      for (int n = 0; n < 4; ++n) {
        fR[s][n][0] = *(const float4*)(Bx + (size_t)n * (16 * 512) + (ks + 2) * 32);
        fR[s][n][1] = *(const float4*)(Bx + (size_t)n * (16 * 512) + (ks + 2) * 32 + 4);
      }
    }
    acc[0] = __builtin_amdgcn_mfma_f32_16x16x32_f16(a, bf[0], acc[0], 0, 0, 0);
    acc[1] = __builtin_amdgcn_mfma_f32_16x16x32_f16(a, bf[1], acc[1], 0, 0, 0);
    acc[2] = __builtin_amdgcn_mfma_f32_16x16x32_f16(a, bf[2], acc[2], 0, 0, 0);
    acc[3] = __builtin_amdgcn_mfma_f32_16x16x32_f16(a, bf[3], acc[3], 0, 0, 0);
  }
  const int r4 = rt * 32 + wv * 16 + (lane >> 4) * 4;
#pragma unroll
  for (int n = 0; n < 4; ++n) {
    uint2 pk;
    pk.x = __builtin_bit_cast(uint32_t,
             __builtin_amdgcn_cvt_pkrtz(acc[n][0], acc[n][1]));
    pk.y = __builtin_bit_cast(uint32_t,
             __builtin_amdgcn_cvt_pkrtz(acc[n][2], acc[n][3]));
    *(uint2*)(y + (size_t)(ct * 64 + n * 16 + l16) * 512 + r4) = pk;
  }
}

// ---------------- kernel 5: apply2, out^T = Q1^T y^T, +bias, f32 out -------
__global__ __launch_bounds__(128) void apply2_kernel(
    const _Float16* __restrict__ Qt1, const _Float16* __restrict__ y,
    const float* __restrict__ bias, float* __restrict__ out) {
  const int rt = blockIdx.x >> 2, ct = blockIdx.x & 3;
  const int lane = threadIdx.x & 63, wv = threadIdx.x >> 6;
  const int l16 = lane & 15, h8 = (lane >> 4) * 8;
  const _Float16* Ap = Qt1 + (size_t)(rt * 32 + wv * 16 + l16) * 512 + h8;
  const _Float16* Bp = y + (size_t)(ct * 64 + l16) * 512 + h8;

  half8_t aR[3]; half8_t bR[3][4];
#pragma unroll
  for (int s = 0; s < 3; ++s) {
    aR[s] = *(const half8_t*)(Ap + s * 32);
#pragma unroll
    for (int n = 0; n < 4; ++n)
      bR[s][n] = *(const half8_t*)(Bp + (size_t)n * (16 * 512) + s * 32);
  }
  f32x4_t acc[4];
#pragma unroll
  for (int n = 0; n < 4; ++n) acc[n] = (f32x4_t){0.f, 0.f, 0.f, 0.f};

#pragma unroll
  for (int ks = 0; ks < 16; ++ks) {
    const int s = ks % 3;
    if (ks <= 13) wait_vm<10>();
    else if (ks == 14) wait_vm<5>();
    else wait_vm<0>();
    half8_t a = aR[s];
    half8_t b0 = bR[s][0], b1 = bR[s][1], b2 = bR[s][2], b3 = bR[s][3];
    if (ks + 3 < 16) {
      aR[s] = *(const half8_t*)(Ap + (ks + 3) * 32);
#pragma unroll
      for (int n = 0; n < 4; ++n)
        bR[s][n] = *(const half8_t*)(Bp + (size_t)n * (16 * 512) + (ks + 3) * 32);
    }
    acc[0] = __builtin_amdgcn_mfma_f32_16x16x32_f16(a, b0, acc[0], 0, 0, 0);
    acc[1] = __builtin_amdgcn_mfma_f32_16x16x32_f16(a, b1, acc[1], 0, 0, 0);
    acc[2] = __builtin_amdgcn_mfma_f32_16x16x32_f16(a, b2, acc[2], 0, 0, 0);
    acc[3] = __builtin_amdgcn_mfma_f32_16x16x32_f16(a, b3, acc[3], 0, 0, 0);
  }
  const int r4 = rt * 32 + wv * 16 + (lane >> 4) * 4;    // out wire c base
  const float4 bv = *(const float4*)(bias + r4);
#pragma unroll
  for (int n = 0; n < 4; ++n) {
    const int b = ct * 64 + n * 16 + l16;                // batch row
    float4 o;
    o.x = acc[n][0] + bv.x;
    o.y = acc[n][1] + bv.y;
    o.z = acc[n][2] + bv.z;
    o.w = acc[n][3] + bv.w;
    *(float4*)(out + (size_t)b * 512 + r4) = o;
  }
}

extern "C" void kernel_launch(void* const* d_in, const int* in_sizes, int n_in,
                              void* d_out, int out_size, void* d_ws,
                              size_t ws_size, hipStream_t stream) {
  const float* x = (const float*)d_in[0];       // (256, 512) f32
  const float* thetas = (const float*)d_in[1];  // (130816,) f32
  const float* bias = (const float*)d_in[2];    // (512,) f32
  float* out = (float*)d_out;                   // (256, 512) f32

  char* ws = (char*)d_ws;                       // uses 8.25 MiB
  uint32_t* W = (uint32_t*)ws;
  _Float16* V = (_Float16*)(ws + OFF_V_BYTES);
  _Float16* P = (_Float16*)(ws + OFF_P_BYTES);
  _Float16* Q = (_Float16*)(ws + OFF_Q_BYTES);
  _Float16* Y = (_Float16*)(ws + OFF_Y_BYTES);

  fused_kernel<<<TOTALH2 / 256, 256, 0, stream>>>(thetas, (__half2*)W);
  window_kernel<<<NWIN * 128, 64, 0, stream>>>(W, V);

  // L1: P0 = V0*V1 (math P0^T -> P0 rows), P1 = V2*V3 (-> P1^T rows),
  //     P2 = V4*V5 (-> rows), P3 = V6*V7 (-> ^T rows).
  Descs4 l1;
  l1.d[0] = {V + 1 * (size_t)V_ELEMS, V + 0 * (size_t)V_ELEMS, P + 0 * (size_t)V_ELEMS};
  l1.d[1] = {V + 2 * (size_t)V_ELEMS, V + 3 * (size_t)V_ELEMS, P + 1 * (size_t)V_ELEMS};
  l1.d[2] = {V + 5 * (size_t)V_ELEMS, V + 4 * (size_t)V_ELEMS, P + 2 * (size_t)V_ELEMS};
  l1.d[3] = {V + 6 * (size_t)V_ELEMS, V + 7 * (size_t)V_ELEMS, P + 3 * (size_t)V_ELEMS};
  gemm512_kernel<<<512, 128, 0, stream>>>(l1);

  // L2: Q0 = P0*P1 -> Q0^T rows; Q1 = P2*P3 -> Q1^T rows.
  Descs4 l2;
  l2.d[0] = {P + 0 * (size_t)V_ELEMS, P + 1 * (size_t)V_ELEMS, Q + 0 * (size_t)V_ELEMS};
  l2.d[1] = {P + 2 * (size_t)V_ELEMS, P + 3 * (size_t)V_ELEMS, Q + 1 * (size_t)V_ELEMS};
  l2.d[2] = l2.d[0];
  l2.d[3] = l2.d[0];
  gemm512_kernel<<<256, 128, 0, stream>>>(l2);

  apply1_kernel<<<64, 128, 0, stream>>>(Q + 0 * (size_t)V_ELEMS, x, Y);
  apply2_kernel<<<64, 128, 0, stream>>>(Q + 1 * (size_t)V_ELEMS, Y, bias, out);
}